// Round 6
// baseline (46.217 us; speedup 1.0000x reference)
//
#include <hip/hip_runtime.h>
#include <math.h>

// CTC forward loss, Keras ctc_batch_cost semantics.
// B=1024, T=256, C=128, L=64, S=2L+1=129, blank=C-1=127.
// Prob-domain forward DP (no per-step transcendentals), power-of-2 rescale
// every 8 steps. Streaming and DP are PIPELINED: 4 groups of 64 rows; after
// each group's barrier, wave 0 advances the DP over the newly available rows
// while waves 1-7 stream the next group (raw s_barrier keeps next-group
// global loads in flight across the barrier; lgkmcnt(0) drains LDS writes).
#define BATCH 1024
#define TT    256
#define CC    128
#define LL    64
#define EPSV  (1e-7f)

typedef float f32x4 __attribute__((ext_vector_type(4)));

// DPP ctrl: row_shr:N = 0x110+N, row_bcast:15 = 0x142, row_bcast:31 = 0x143,
// wave_rol:1 = 0x134.
template <int CTRL>
__device__ __forceinline__ float dpp0(float x) {   // invalid lanes -> 0
    return __int_as_float(__builtin_amdgcn_update_dpp(0, __float_as_int(x), CTRL, 0xF, 0xF, true));
}
template <int CTRL>
__device__ __forceinline__ float dppS(float x) {   // invalid lanes -> self
    return __int_as_float(__builtin_amdgcn_update_dpp(__float_as_int(x), __float_as_int(x), CTRL, 0xF, 0xF, false));
}
__device__ __forceinline__ float rol1_f(float x) { // lane i <- lane (i-1)&63
    return __int_as_float(__builtin_amdgcn_update_dpp(__float_as_int(x), __float_as_int(x), 0x134, 0xF, 0xF, false));
}
__device__ __forceinline__ int rol1_i(int x) {
    return __builtin_amdgcn_update_dpp(x, x, 0x134, 0xF, 0xF, false);
}
__device__ __forceinline__ float rdlane(float x, int l) {
    return __int_as_float(__builtin_amdgcn_readlane(__float_as_int(x), l));
}
__device__ __forceinline__ float wave_max_bcast(float m) {
    m = fmaxf(m, dppS<0x111>(m));
    m = fmaxf(m, dppS<0x112>(m));
    m = fmaxf(m, dppS<0x114>(m));
    m = fmaxf(m, dppS<0x118>(m));
    m = fmaxf(m, dppS<0x142>(m));
    m = fmaxf(m, dppS<0x143>(m));
    return rdlane(m, 63);
}
__device__ __forceinline__ unsigned f2h(float x) { // fp32 -> fp16 bits (RTN)
    _Float16 h = (_Float16)x;
    unsigned short u; __builtin_memcpy(&u, &h, 2);
    return (unsigned)u;
}
__device__ __forceinline__ float h2f(unsigned short u) {
    _Float16 h; __builtin_memcpy(&h, &u, 2);
    return (float)h;
}

__global__ __launch_bounds__(512, 8) void ctc_fwd_kernel(const int* __restrict__ y_true,
                                                         const float* __restrict__ y_pred,
                                                         float* __restrict__ out) {
    __shared__ unsigned short qtab[TT][66];  // q[t][l] = p[t][yt[l]]+eps (fp16 bits)
    __shared__ float qblank[TT];             // q[t][blank]
    __shared__ float logZpart[8];

    const int b    = blockIdx.x;
    const int tid  = threadIdx.x;
    const int wv   = tid >> 6;
    const int lane = tid & 63;

    const float* yp = y_pred + (size_t)b * (TT * CC);
    const int lab  = y_true[b * LL + lane];  // lane l holds label l (l<64)
    const int srcA = lab >> 2;               // source lane for row part A
    const int srcB = 32 + srcA;              // ... row part B
    const bool hiPair = (lab & 2) != 0;
    const bool hiHalf = (lab & 1) != 0;

    // float4 covers 2 rows: lanes 0-31 -> row 2*r2, lanes 32-63 -> row 2*r2+1.
    const int off = ((lane >> 5) << 7) + ((lane & 31) << 2);
    const float* base = yp + off;

    // DP persistent state (meaningful on wave 0)
    const int   labm1 = rol1_i(lab);
    const float mskip = (lane >= 1 && lab != labm1) ? 1.0f : 0.0f;
    const bool  l0 = (lane == 0);
    float a0 = 0.0f, a1 = 0.0f, aX = 0.0f;
    int   Esum = 0;
    float zacc = 0.0f;                       // meaningful on lanes 31/63

    f32x4 v[4];
    #pragma unroll
    for (int j = 0; j < 4; ++j)
        v[j] = *(const f32x4*)(base + 256 * (wv + 8 * j));

    #pragma unroll
    for (int g = 0; g < 4; ++g) {
        // ---- process group g: rows 64g .. 64g+63 ----
        #pragma unroll
        for (int j = 0; j < 4; ++j) {
            const int r2 = wv + 32 * g + 8 * j;
            const int tA = 2 * r2, tB = tA + 1;
            float q0 = v[j][0] + EPSV, q1 = v[j][1] + EPSV;
            float q2 = v[j][2] + EPSV, q3 = v[j][3] + EPSV;
            // half-wave reduce: row-A total -> lane 31, row-B total -> lane 63
            float s = (q0 + q1) + (q2 + q3);
            s += dpp0<0x111>(s);
            s += dpp0<0x112>(s);
            s += dpp0<0x114>(s);
            s += dpp0<0x118>(s);
            s += dpp0<0x142>(s);
            zacc += __logf(s);               // garbage off lanes 31/63 (finite)
            // pack own 4 cols to fp16 pairs, gather via register shuffles
            int i01 = (int)(f2h(q0) | (f2h(q1) << 16));
            int i23 = (int)(f2h(q2) | (f2h(q3) << 16));
            int gA01 = __shfl(i01, srcA), gA23 = __shfl(i23, srcA);
            int gB01 = __shfl(i01, srcB), gB23 = __shfl(i23, srcB);
            int sA = hiPair ? gA23 : gA01;
            int sB = hiPair ? gB23 : gB01;
            qtab[tA][lane] = (unsigned short)(hiHalf ? ((unsigned)sA >> 16) : (sA & 0xFFFF));
            qtab[tB][lane] = (unsigned short)(hiHalf ? ((unsigned)sB >> 16) : (sB & 0xFFFF));
            if ((lane & 31) == 31) qblank[tA + (lane >> 5)] = q3;   // col 127 == blank
        }
        // ---- issue next group's loads (stay in flight across the barrier) ----
        if (g < 3) {
            #pragma unroll
            for (int j = 0; j < 4; ++j)
                v[j] = *(const f32x4*)(base + 256 * (wv + 32 * (g + 1) + 8 * j));
        }
        if (g == 3) {
            float z31 = rdlane(zacc, 31), z63 = rdlane(zacc, 63);
            if (lane == 0) logZpart[wv] = z31 + z63;
        }
        // raw barrier: drain LDS writes only; global loads survive.
        asm volatile("s_waitcnt lgkmcnt(0)" ::: "memory");
        __builtin_amdgcn_s_barrier();
        __builtin_amdgcn_sched_barrier(0);

        // ---- wave 0: advance DP over rows now available (< 64g+64) ----
        if (wv == 0) {
            __builtin_amdgcn_s_setprio(1);
            if (g == 0) {
                // t=0 init: alpha[0]=q0[blank], alpha[1]=q0[yt[0]], rest 0.
                a0 = l0 ? qblank[0] : 0.0f;
                a1 = l0 ? h2f(qtab[0][lane]) : 0.0f;
                aX = 0.0f;
            }
            const int s0 = (g == 0) ? 1 : (64 * g - 7);   // 1, 57, 121, 185
            const int nc = (g == 0) ? 7 : 8;              // chunks of 8 steps
            for (int c = 0; c < nc; ++c) {
                const int s = s0 + 8 * c;
                float qb[8], ql[8];
                #pragma unroll
                for (int i = 0; i < 8; ++i) {
                    qb[i] = qblank[s + i];
                    ql[i] = h2f(qtab[s + i][lane]);
                }
                #pragma unroll
                for (int i = 0; i < 8; ++i) {
                    float nb  = rol1_f(a1);               // alpha[2*lane-1]
                    float na0 = (a0 + (l0 ? 0.0f : nb)) * qb[i];
                    float na1 = fmaf(mskip, nb, a0 + a1) * ql[i];
                    aX = l0 ? (aX + nb) * qb[i] : 0.0f;
                    a0 = na0; a1 = na1;
                }
                // power-of-2 rescale once per chunk
                float m = fmaxf(fmaxf(a0, a1), aX);
                float mall = wave_max_bcast(m);
                int ex = (int)((__float_as_uint(mall) >> 23) & 0xFF);
                int e  = 127 - ex;
                float sc = __uint_as_float((unsigned)(127 + e) << 23);
                a0 *= sc; a1 *= sc; aX *= sc;
                Esum += e;
            }
            __builtin_amdgcn_s_setprio(0);
        }
    }

    // ---- wave 0 epilogue: t = 249..255, then output ----
    if (wv == 0) {
        #pragma unroll
        for (int i = 0; i < 7; ++i) {
            float qb = qblank[249 + i];
            float ql = h2f(qtab[249 + i][lane]);
            float nb  = rol1_f(a1);
            float na0 = (a0 + (l0 ? 0.0f : nb)) * qb;
            float na1 = fmaf(mskip, nb, a0 + a1) * ql;
            aX = l0 ? (aX + nb) * qb : 0.0f;
            a0 = na0; a1 = na1;
        }
        float LZ = 0.0f;
        #pragma unroll
        for (int w = 0; w < 8; ++w) LZ += logZpart[w];
        float a127 = rdlane(a1, 63);
        if (lane == 0) {
            float tot = aX + a127;                  // alpha[128] + alpha[127]
            out[b] = LZ + (float)Esum * 0.69314718055994531f - __logf(tot);
        }
    }
}

extern "C" void kernel_launch(void* const* d_in, const int* in_sizes, int n_in,
                              void* d_out, int out_size, void* d_ws, size_t ws_size,
                              hipStream_t stream) {
    const int*   y_true = (const int*)d_in[0];
    const float* y_pred = (const float*)d_in[1];
    float*       out    = (float*)d_out;
    ctc_fwd_kernel<<<BATCH, 512, 0, stream>>>(y_true, y_pred, out);
}